// Round 11
// baseline (518.119 us; speedup 1.0000x reference)
//
#include <hip/hip_runtime.h>
#include <hip/hip_bf16.h>
#include <math.h>

#define NEG_SLOPE 0.2f

// ------- GEMM f32: BMx BN tile, BK=16, 256 thr, split-fragment micro -------
// TM=8 always (rows ty*4+i and BM/2+ty*4+i); TN = 8 (cols tx*4, BN/2+tx*4)
// or 4 (cols tx*4). A-reads broadcast (4 addrs/wave), B-reads consecutive
// float4 across 16 lanes -> conflict-free.
template <int BM_, int BN_, int TN_>
__global__ __launch_bounds__(256) void gemm_f32_t(const float* __restrict__ A,
                                                  const float* __restrict__ B,
                                                  float* __restrict__ C,
                                                  int M, int N, int K) {
  constexpr int BK_ = 16;
  constexpr int NJH = TN_ / 4;                 // 1 or 2 column halves
  __shared__ float As[BK_][BM_ + 4];
  __shared__ float Bs[BK_][BN_ + 4];
  const int tid = threadIdx.x;
  const int tx = tid & 15;
  const int ty = tid >> 4;
  const int bm = blockIdx.x * BM_;
  const int bn = blockIdx.y * BN_;
  float acc[2][NJH][4][4] = {};
  for (int k0 = 0; k0 < K; k0 += BK_) {
    // stage A: BM_ rows x 16 K, transposed into As[k][m]
    #pragma unroll
    for (int i = tid; i < BM_ * 4; i += 256) {
      int r = i >> 2, c4 = i & 3;
      int gr = bm + r;
      float4 v = make_float4(0.f, 0.f, 0.f, 0.f);
      if (gr < M) v = *reinterpret_cast<const float4*>(&A[(size_t)gr * K + k0 + c4 * 4]);
      As[c4 * 4 + 0][r] = v.x;
      As[c4 * 4 + 1][r] = v.y;
      As[c4 * 4 + 2][r] = v.z;
      As[c4 * 4 + 3][r] = v.w;
    }
    // stage B: 16 K x BN_ cols, row-major
    #pragma unroll
    for (int i = tid; i < BN_ * 4; i += 256) {
      constexpr int F4 = BN_ / 4;
      int r = i / F4, c4 = i % F4;
      *reinterpret_cast<float4*>(&Bs[r][c4 * 4]) =
          *reinterpret_cast<const float4*>(&B[(size_t)(k0 + r) * N + bn + c4 * 4]);
    }
    __syncthreads();
    #pragma unroll
    for (int kk = 0; kk < BK_; ++kk) {
      float4 a0 = *reinterpret_cast<const float4*>(&As[kk][ty * 4]);
      float4 a1 = *reinterpret_cast<const float4*>(&As[kk][BM_ / 2 + ty * 4]);
      float av[2][4] = {{a0.x, a0.y, a0.z, a0.w}, {a1.x, a1.y, a1.z, a1.w}};
      float bv[NJH][4];
      {
        float4 b0 = *reinterpret_cast<const float4*>(&Bs[kk][tx * 4]);
        bv[0][0] = b0.x; bv[0][1] = b0.y; bv[0][2] = b0.z; bv[0][3] = b0.w;
      }
      if constexpr (NJH == 2) {
        float4 b1 = *reinterpret_cast<const float4*>(&Bs[kk][BN_ / 2 + tx * 4]);
        bv[1][0] = b1.x; bv[1][1] = b1.y; bv[1][2] = b1.z; bv[1][3] = b1.w;
      }
      #pragma unroll
      for (int ih = 0; ih < 2; ++ih)
        #pragma unroll
        for (int jh = 0; jh < NJH; ++jh)
          #pragma unroll
          for (int i = 0; i < 4; ++i)
            #pragma unroll
            for (int j = 0; j < 4; ++j)
              acc[ih][jh][i][j] += av[ih][i] * bv[jh][j];
    }
    __syncthreads();
  }
  #pragma unroll
  for (int ih = 0; ih < 2; ++ih) {
    #pragma unroll
    for (int i = 0; i < 4; ++i) {
      int gr = bm + ih * (BM_ / 2) + ty * 4 + i;
      if (gr < M) {
        #pragma unroll
        for (int jh = 0; jh < NJH; ++jh) {
          float4 v = make_float4(acc[ih][jh][i][0], acc[ih][jh][i][1],
                                 acc[ih][jh][i][2], acc[ih][jh][i][3]);
          *reinterpret_cast<float4*>(&C[(size_t)gr * N + bn + jh * (BN_ / 2) + tx * 4]) = v;
        }
      }
    }
  }
}

// ---------------- node init: self-loop degree + cursor ----------------------
__global__ void init_nodes(int* deg, int* cursor, int N) {
  int n = blockIdx.x * blockDim.x + threadIdx.x;
  if (n >= N) return;
  deg[n] = 1;        // self loop
  cursor[n] = 0;
}

// ---------------- degree count over real edges ------------------------------
__global__ void count_deg(const int* __restrict__ ei, int E, int* __restrict__ deg) {
  int i = blockIdx.x * blockDim.x + threadIdx.x;
  if (i >= E) return;
  atomicAdd(&deg[ei[E + i]], 1);     // ei[E + i] = dst
}

// ---------------- exclusive scan of degrees (single block) ------------------
__global__ __launch_bounds__(1024) void scan_deg(const int* __restrict__ deg,
                                                 int* __restrict__ off, int N) {
  __shared__ int partial[1024];
  int tid = threadIdx.x;
  int chunk = (N + 1023) / 1024;
  int start = tid * chunk;
  int end = min(start + chunk, N);
  int sum = 0;
  for (int i = start; i < end; ++i) sum += deg[i];
  partial[tid] = sum;
  __syncthreads();
  for (int s = 1; s < 1024; s <<= 1) {
    int v = (tid >= s) ? partial[tid - s] : 0;
    __syncthreads();
    partial[tid] += v;
    __syncthreads();
  }
  int run = (tid == 0) ? 0 : partial[tid - 1];
  for (int i = start; i < end; ++i) { off[i] = run; run += deg[i]; }
  if (tid == 1023) off[N] = partial[1023];
}

// ---------------- CSR fill (src list grouped by dst) ------------------------
__global__ void fill_csr(const int* __restrict__ ei, int E, int N,
                         const int* __restrict__ off, int* __restrict__ cursor,
                         int* __restrict__ srcs) {
  int i = blockIdx.x * blockDim.x + threadIdx.x;
  int total = E + N;
  if (i >= total) return;
  int s, d;
  if (i < E) { s = ei[i]; d = ei[E + i]; }
  else       { s = d = i - E; }            // self loops
  int pos = off[d] + atomicAdd(&cursor[d], 1);
  srcs[pos] = s;
}

// ---------------- per-(node,head) attention logits, layer 1 -----------------
__global__ void scores1(const float* __restrict__ h1, const float* __restrict__ att_s,
                        const float* __restrict__ att_d, float* __restrict__ a_s,
                        float* __restrict__ a_d, int N) {
  int idx = blockIdx.x * blockDim.x + threadIdx.x;
  if (idx >= N * 8) return;
  int hh = idx & 7;
  const float4* row = reinterpret_cast<const float4*>(h1 + (size_t)(idx >> 3) * 256 + hh * 32);
  const float4* as4 = reinterpret_cast<const float4*>(att_s) + hh * 8;
  const float4* ad4 = reinterpret_cast<const float4*>(att_d) + hh * 8;
  float ss = 0.f, dd = 0.f;
  #pragma unroll
  for (int c = 0; c < 8; ++c) {
    float4 v = row[c], s4 = as4[c], d4 = ad4[c];
    ss += v.x * s4.x + v.y * s4.y + v.z * s4.z + v.w * s4.w;
    dd += v.x * d4.x + v.y * d4.y + v.z * d4.z + v.w * d4.w;
  }
  a_s[idx] = ss;
  a_d[idx] = dd;
}

// ------ layer-1 aggregation, fused softmax: 1 wave per node, 4 nodes/block --
// 8 row-gathers in flight; predicated 8-deep tail keeps MLP on remainders.
__global__ __launch_bounds__(256) void aggregate1(const int* __restrict__ off,
                                                  const int* __restrict__ srcs,
                                                  const float* __restrict__ a_s,
                                                  const float* __restrict__ a_d,
                                                  const float* __restrict__ h1,
                                                  const float* __restrict__ b1,
                                                  float* __restrict__ y1, int N) {
  int n = blockIdx.x * 4 + (threadIdx.x >> 6);
  if (n >= N) return;
  int lane = threadIdx.x & 63;
  int hh = lane >> 3;
  float adh = a_d[n * 8 + hh];
  int beg = off[n], end = off[n + 1];
  float4 acc = make_float4(0.f, 0.f, 0.f, 0.f);
  float sw = 0.f;
  int p = beg;
  for (; p + 8 <= end; p += 8) {
    int s[8]; float4 v[8]; float w[8];
    #pragma unroll
    for (int j = 0; j < 8; ++j) s[j] = srcs[p + j];
    #pragma unroll
    for (int j = 0; j < 8; ++j)
      v[j] = *reinterpret_cast<const float4*>(h1 + (size_t)s[j] * 256 + lane * 4);
    #pragma unroll
    for (int j = 0; j < 8; ++j) {
      float e = a_s[s[j] * 8 + hh] + adh;
      e = e > 0.f ? e : NEG_SLOPE * e;
      w[j] = __expf(e);
    }
    #pragma unroll
    for (int j = 0; j < 8; ++j) {
      sw += w[j];
      acc.x += w[j] * v[j].x; acc.y += w[j] * v[j].y;
      acc.z += w[j] * v[j].z; acc.w += w[j] * v[j].w;
    }
  }
  if (p < end) {                       // predicated tail: 1..7 edges, 8 loads in flight
    int cnt = end - p;
    int s[8]; float4 v[8]; float w[8];
    #pragma unroll
    for (int j = 0; j < 8; ++j) s[j] = srcs[p + (j < cnt ? j : cnt - 1)];
    #pragma unroll
    for (int j = 0; j < 8; ++j)
      v[j] = *reinterpret_cast<const float4*>(h1 + (size_t)s[j] * 256 + lane * 4);
    #pragma unroll
    for (int j = 0; j < 8; ++j) {
      float e = a_s[s[j] * 8 + hh] + adh;
      e = e > 0.f ? e : NEG_SLOPE * e;
      w[j] = (j < cnt) ? __expf(e) : 0.f;
    }
    #pragma unroll
    for (int j = 0; j < 8; ++j) {
      sw += w[j];
      acc.x += w[j] * v[j].x; acc.y += w[j] * v[j].y;
      acc.z += w[j] * v[j].z; acc.w += w[j] * v[j].w;
    }
  }
  float inv = 1.f / (sw + 1e-16f);
  float4 b = reinterpret_cast<const float4*>(b1)[lane];
  float4 r;
  r.x = acc.x * inv + b.x;
  r.y = acc.y * inv + b.y;
  r.z = acc.z * inv + b.z;
  r.w = acc.w * inv + b.w;
  r.x = r.x > 0.f ? r.x : (__expf(r.x) - 1.f);   // ELU
  r.y = r.y > 0.f ? r.y : (__expf(r.y) - 1.f);
  r.z = r.z > 0.f ? r.z : (__expf(r.z) - 1.f);
  r.w = r.w > 0.f ? r.w : (__expf(r.w) - 1.f);
  *reinterpret_cast<float4*>(y1 + (size_t)n * 256 + lane * 4) = r;
}

// ---------------- per-node attention logits, layer 2 ------------------------
__global__ void scores2(const float* __restrict__ h2, const float* __restrict__ att_s,
                        const float* __restrict__ att_d, float* __restrict__ a_s,
                        float* __restrict__ a_d, int N) {
  int n = blockIdx.x * blockDim.x + threadIdx.x;
  if (n >= N) return;
  const float4* row = reinterpret_cast<const float4*>(h2 + (size_t)n * 64);
  const float4* as4 = reinterpret_cast<const float4*>(att_s);
  const float4* ad4 = reinterpret_cast<const float4*>(att_d);
  float ss = 0.f, dd = 0.f;
  #pragma unroll
  for (int c = 0; c < 16; ++c) {
    float4 v = row[c], s4 = as4[c], d4 = ad4[c];
    ss += v.x * s4.x + v.y * s4.y + v.z * s4.z + v.w * s4.w;
    dd += v.x * d4.x + v.y * d4.y + v.z * d4.z + v.w * d4.w;
  }
  a_s[n] = ss;
  a_d[n] = dd;
}

// ------ layer-2 aggregation, fused softmax: 1 wave/node, lane = channel -----
__global__ __launch_bounds__(256) void aggregate2(const int* __restrict__ off,
                                                  const int* __restrict__ srcs,
                                                  const float* __restrict__ a_s,
                                                  const float* __restrict__ a_d,
                                                  const float* __restrict__ h2,
                                                  const float* __restrict__ b2,
                                                  float* __restrict__ out, int N) {
  int n = blockIdx.x * 4 + (threadIdx.x >> 6);
  if (n >= N) return;
  int c = threadIdx.x & 63;            // channel 0..63
  float ad = a_d[n];
  int beg = off[n], end = off[n + 1];
  float acc = 0.f;
  float sw = 0.f;
  int p = beg;
  for (; p + 8 <= end; p += 8) {
    int s[8]; float v[8]; float w[8];
    #pragma unroll
    for (int j = 0; j < 8; ++j) s[j] = srcs[p + j];
    #pragma unroll
    for (int j = 0; j < 8; ++j) v[j] = h2[(size_t)s[j] * 64 + c];
    #pragma unroll
    for (int j = 0; j < 8; ++j) {
      float e = a_s[s[j]] + ad;
      e = e > 0.f ? e : NEG_SLOPE * e;
      w[j] = __expf(e);
    }
    #pragma unroll
    for (int j = 0; j < 8; ++j) { sw += w[j]; acc += w[j] * v[j]; }
  }
  if (p < end) {                       // predicated tail
    int cnt = end - p;
    int s[8]; float v[8]; float w[8];
    #pragma unroll
    for (int j = 0; j < 8; ++j) s[j] = srcs[p + (j < cnt ? j : cnt - 1)];
    #pragma unroll
    for (int j = 0; j < 8; ++j) v[j] = h2[(size_t)s[j] * 64 + c];
    #pragma unroll
    for (int j = 0; j < 8; ++j) {
      float e = a_s[s[j]] + ad;
      e = e > 0.f ? e : NEG_SLOPE * e;
      w[j] = (j < cnt) ? __expf(e) : 0.f;
    }
    #pragma unroll
    for (int j = 0; j < 8; ++j) { sw += w[j]; acc += w[j] * v[j]; }
  }
  out[(size_t)n * 64 + c] = acc / (sw + 1e-16f) + b2[c];   // heads=1: mean==id
}

extern "C" void kernel_launch(void* const* d_in, const int* in_sizes, int n_in,
                              void* d_out, int out_size, void* d_ws, size_t ws_size,
                              hipStream_t stream) {
  const float* x   = (const float*)d_in[0];
  const int*   ei  = (const int*)d_in[1];
  const float* W1  = (const float*)d_in[2];
  const float* as1 = (const float*)d_in[3];
  const float* ad1 = (const float*)d_in[4];
  const float* b1  = (const float*)d_in[5];
  const float* W2  = (const float*)d_in[6];
  const float* as2 = (const float*)d_in[7];
  const float* ad2 = (const float*)d_in[8];
  const float* b2  = (const float*)d_in[9];
  float* out = (float*)d_out;

  const int N = in_sizes[0] / 128;   // 50000
  const int E = in_sizes[1] / 2;     // 800000
  const int T = E + N;               // edge slots incl self loops

  // -------- workspace layout (~108 MB peak, layer-2 aliases layer-1) --------
  char* w = (char*)d_ws;
  size_t o = 0;
  auto alloc = [&](size_t bytes) -> void* {
    void* p = w + o;
    o += (bytes + 255) & ~(size_t)255;
    return p;
  };
  float* h1   = (float*)alloc((size_t)N * 256 * 4);   // dead after aggregate1
  float* y1   = (float*)alloc((size_t)N * 256 * 4);
  float* a_s1 = (float*)alloc((size_t)N * 8 * 4);     // dead after aggregate1
  float* a_d1 = (float*)alloc((size_t)N * 8 * 4);     // dead after aggregate1
  int*   deg  = (int*)alloc((size_t)N * 4);
  int*   off  = (int*)alloc((size_t)(N + 1) * 4);
  int*   cur  = (int*)alloc((size_t)N * 4);
  int*   srcs = (int*)alloc((size_t)T * 4);
  // layer-2 aliases (strictly after last read of the aliased buffer):
  float* h2   = h1;                   // 12.8 MB into h1's 51.2 MB
  float* a_s2 = a_s1;
  float* a_d2 = a_d1;

  // -------- CSR build (shared by both layers) --------
  init_nodes<<<(N + 255) / 256, 256, 0, stream>>>(deg, cur, N);
  count_deg<<<(E + 255) / 256, 256, 0, stream>>>(ei, E, deg);
  scan_deg<<<1, 1024, 0, stream>>>(deg, off, N);
  fill_csr<<<(T + 255) / 256, 256, 0, stream>>>(ei, E, N, off, cur, srcs);

  // -------- layer 1: h1 = x @ W1  (50000x128 @ 128x256) --------
  dim3 g1((N + 127) / 128, 2);       // BN=128, N=256
  gemm_f32_t<128, 128, 8><<<g1, 256, 0, stream>>>(x, W1, h1, N, 256, 128);
  scores1<<<(N * 8 + 255) / 256, 256, 0, stream>>>(h1, as1, ad1, a_s1, a_d1, N);
  aggregate1<<<(N + 3) / 4, 256, 0, stream>>>(off, srcs, a_s1, a_d1, h1, b1, y1, N);

  // -------- layer 2: h2 = y1 @ W2  (50000x256 @ 256x64) --------
  dim3 g2((N + 127) / 128, 1);       // BN=64, N=64
  gemm_f32_t<128, 64, 4><<<g2, 256, 0, stream>>>(y1, W2, h2, N, 64, 256);
  scores2<<<(N + 255) / 256, 256, 0, stream>>>(h2, as2, ad2, a_s2, a_d2, N);
  aggregate2<<<(N + 3) / 4, 256, 0, stream>>>(off, srcs, a_s2, a_d2, h2, b2, out, N);
}

// Round 12
// 460.737 us; speedup vs baseline: 1.1245x; 1.1245x over previous
//
#include <hip/hip_runtime.h>
#include <hip/hip_bf16.h>
#include <math.h>

#define NEG_SLOPE 0.2f

// RNE float->bf16 pair pack (finite data; NaN not handled)
__device__ __forceinline__ unsigned int pack_bf16x2(float a, float b) {
  unsigned ua = __float_as_uint(a); ua = ua + 0x7fffu + ((ua >> 16) & 1u);
  unsigned ub = __float_as_uint(b); ub = ub + 0x7fffu + ((ub >> 16) & 1u);
  return (ua >> 16) | (ub & 0xffff0000u);
}

// ------- GEMM f32: BMxBN tile, BK=16, 256 thr, split-fragment micro -------
// CT=float: float4 C-store. CT=ushort: bf16 C-store (uint2 per 4 cols).
template <int BM_, int BN_, int TN_, typename CT>
__global__ __launch_bounds__(256) void gemm_f32_t(const float* __restrict__ A,
                                                  const float* __restrict__ B,
                                                  CT* __restrict__ C,
                                                  int M, int N, int K) {
  constexpr int BK_ = 16;
  constexpr int NJH = TN_ / 4;                 // 1 or 2 column halves
  __shared__ float As[BK_][BM_ + 4];
  __shared__ float Bs[BK_][BN_ + 4];
  const int tid = threadIdx.x;
  const int tx = tid & 15;
  const int ty = tid >> 4;
  const int bm = blockIdx.x * BM_;
  const int bn = blockIdx.y * BN_;
  float acc[2][NJH][4][4] = {};
  for (int k0 = 0; k0 < K; k0 += BK_) {
    #pragma unroll
    for (int i = tid; i < BM_ * 4; i += 256) {   // A: BM_ rows x 16K, transposed
      int r = i >> 2, c4 = i & 3;
      int gr = bm + r;
      float4 v = make_float4(0.f, 0.f, 0.f, 0.f);
      if (gr < M) v = *reinterpret_cast<const float4*>(&A[(size_t)gr * K + k0 + c4 * 4]);
      As[c4 * 4 + 0][r] = v.x;
      As[c4 * 4 + 1][r] = v.y;
      As[c4 * 4 + 2][r] = v.z;
      As[c4 * 4 + 3][r] = v.w;
    }
    #pragma unroll
    for (int i = tid; i < BN_ * 4; i += 256) {   // B: 16K x BN_, row-major
      constexpr int F4 = BN_ / 4;
      int r = i / F4, c4 = i % F4;
      *reinterpret_cast<float4*>(&Bs[r][c4 * 4]) =
          *reinterpret_cast<const float4*>(&B[(size_t)(k0 + r) * N + bn + c4 * 4]);
    }
    __syncthreads();
    #pragma unroll
    for (int kk = 0; kk < BK_; ++kk) {
      float4 a0 = *reinterpret_cast<const float4*>(&As[kk][ty * 4]);
      float4 a1 = *reinterpret_cast<const float4*>(&As[kk][BM_ / 2 + ty * 4]);
      float av[2][4] = {{a0.x, a0.y, a0.z, a0.w}, {a1.x, a1.y, a1.z, a1.w}};
      float bv[NJH][4];
      {
        float4 b0 = *reinterpret_cast<const float4*>(&Bs[kk][tx * 4]);
        bv[0][0] = b0.x; bv[0][1] = b0.y; bv[0][2] = b0.z; bv[0][3] = b0.w;
      }
      if constexpr (NJH == 2) {
        float4 b1 = *reinterpret_cast<const float4*>(&Bs[kk][BN_ / 2 + tx * 4]);
        bv[1][0] = b1.x; bv[1][1] = b1.y; bv[1][2] = b1.z; bv[1][3] = b1.w;
      }
      #pragma unroll
      for (int ih = 0; ih < 2; ++ih)
        #pragma unroll
        for (int jh = 0; jh < NJH; ++jh)
          #pragma unroll
          for (int i = 0; i < 4; ++i)
            #pragma unroll
            for (int j = 0; j < 4; ++j)
              acc[ih][jh][i][j] += av[ih][i] * bv[jh][j];
    }
    __syncthreads();
  }
  #pragma unroll
  for (int ih = 0; ih < 2; ++ih) {
    #pragma unroll
    for (int i = 0; i < 4; ++i) {
      int gr = bm + ih * (BM_ / 2) + ty * 4 + i;
      if (gr < M) {
        #pragma unroll
        for (int jh = 0; jh < NJH; ++jh) {
          size_t cidx = (size_t)gr * N + bn + jh * (BN_ / 2) + tx * 4;
          if constexpr (sizeof(CT) == 4) {
            float4 v = make_float4(acc[ih][jh][i][0], acc[ih][jh][i][1],
                                   acc[ih][jh][i][2], acc[ih][jh][i][3]);
            *reinterpret_cast<float4*>(&C[cidx]) = v;
          } else {
            uint2 q;
            q.x = pack_bf16x2(acc[ih][jh][i][0], acc[ih][jh][i][1]);
            q.y = pack_bf16x2(acc[ih][jh][i][2], acc[ih][jh][i][3]);
            *reinterpret_cast<uint2*>(&C[cidx]) = q;
          }
        }
      }
    }
  }
}

// ---------------- node init: self-loop degree + cursor ----------------------
__global__ void init_nodes(int* deg, int* cursor, int N) {
  int n = blockIdx.x * blockDim.x + threadIdx.x;
  if (n >= N) return;
  deg[n] = 1;        // self loop
  cursor[n] = 0;
}

// ---------------- degree count over real edges ------------------------------
__global__ void count_deg(const int* __restrict__ ei, int E, int* __restrict__ deg) {
  int i = blockIdx.x * blockDim.x + threadIdx.x;
  if (i >= E) return;
  atomicAdd(&deg[ei[E + i]], 1);     // ei[E + i] = dst
}

// ---------------- exclusive scan of degrees (single block) ------------------
__global__ __launch_bounds__(1024) void scan_deg(const int* __restrict__ deg,
                                                 int* __restrict__ off, int N) {
  __shared__ int partial[1024];
  int tid = threadIdx.x;
  int chunk = (N + 1023) / 1024;
  int start = tid * chunk;
  int end = min(start + chunk, N);
  int sum = 0;
  for (int i = start; i < end; ++i) sum += deg[i];
  partial[tid] = sum;
  __syncthreads();
  for (int s = 1; s < 1024; s <<= 1) {
    int v = (tid >= s) ? partial[tid - s] : 0;
    __syncthreads();
    partial[tid] += v;
    __syncthreads();
  }
  int run = (tid == 0) ? 0 : partial[tid - 1];
  for (int i = start; i < end; ++i) { off[i] = run; run += deg[i]; }
  if (tid == 1023) off[N] = partial[1023];
}

// ---------------- CSR fill (src list grouped by dst) ------------------------
__global__ void fill_csr(const int* __restrict__ ei, int E, int N,
                         const int* __restrict__ off, int* __restrict__ cursor,
                         int* __restrict__ srcs) {
  int i = blockIdx.x * blockDim.x + threadIdx.x;
  int total = E + N;
  if (i >= total) return;
  int s, d;
  if (i < E) { s = ei[i]; d = ei[E + i]; }
  else       { s = d = i - E; }            // self loops
  int pos = off[d] + atomicAdd(&cursor[d], 1);
  srcs[pos] = s;
}

// ------- per-(node,head) attention logits, layer 1 (bf16 h1 input) ----------
__global__ void scores1(const unsigned short* __restrict__ h1b,
                        const float* __restrict__ att_s,
                        const float* __restrict__ att_d, float* __restrict__ a_s,
                        float* __restrict__ a_d, int N) {
  int idx = blockIdx.x * blockDim.x + threadIdx.x;
  if (idx >= N * 8) return;
  int hh = idx & 7;
  const uint4* row = reinterpret_cast<const uint4*>(h1b + (size_t)(idx >> 3) * 256 + hh * 32);
  const float* as = att_s + hh * 32;
  const float* ad = att_d + hh * 32;
  float ss = 0.f, dd = 0.f;
  #pragma unroll
  for (int c = 0; c < 4; ++c) {
    uint4 q = row[c];
    unsigned qs[4] = {q.x, q.y, q.z, q.w};
    #pragma unroll
    for (int k = 0; k < 4; ++k) {
      float f0 = __uint_as_float(qs[k] << 16);
      float f1 = __uint_as_float(qs[k] & 0xffff0000u);
      int ch = c * 8 + k * 2;
      ss += f0 * as[ch] + f1 * as[ch + 1];
      dd += f0 * ad[ch] + f1 * ad[ch + 1];
    }
  }
  a_s[idx] = ss;
  a_d[idx] = dd;
}

// ------ layer-1 aggregation, fused softmax, bf16 gather: 1 wave/node --------
// lane -> channels lane*4..+3 (8B bf16/lane, 512B/row coalesced), head=lane>>3.
__global__ __launch_bounds__(256) void aggregate1(const int* __restrict__ off,
                                                  const int* __restrict__ srcs,
                                                  const float* __restrict__ a_s,
                                                  const float* __restrict__ a_d,
                                                  const unsigned short* __restrict__ h1b,
                                                  const float* __restrict__ b1,
                                                  float* __restrict__ y1, int N) {
  int n = blockIdx.x * 4 + (threadIdx.x >> 6);
  if (n >= N) return;
  int lane = threadIdx.x & 63;
  int hh = lane >> 3;
  float adh = a_d[n * 8 + hh];
  int beg = off[n], end = off[n + 1];
  float4 acc = make_float4(0.f, 0.f, 0.f, 0.f);
  float sw = 0.f;
  int p = beg;
  for (; p + 8 <= end; p += 8) {
    int s[8]; uint2 v[8]; float w[8];
    #pragma unroll
    for (int j = 0; j < 8; ++j) s[j] = srcs[p + j];
    #pragma unroll
    for (int j = 0; j < 8; ++j)
      v[j] = *reinterpret_cast<const uint2*>(h1b + (size_t)s[j] * 256 + lane * 4);
    #pragma unroll
    for (int j = 0; j < 8; ++j) {
      float e = a_s[s[j] * 8 + hh] + adh;
      e = e > 0.f ? e : NEG_SLOPE * e;
      w[j] = __expf(e);
    }
    #pragma unroll
    for (int j = 0; j < 8; ++j) {
      float c0 = __uint_as_float(v[j].x << 16);
      float c1 = __uint_as_float(v[j].x & 0xffff0000u);
      float c2 = __uint_as_float(v[j].y << 16);
      float c3 = __uint_as_float(v[j].y & 0xffff0000u);
      sw += w[j];
      acc.x += w[j] * c0; acc.y += w[j] * c1;
      acc.z += w[j] * c2; acc.w += w[j] * c3;
    }
  }
  if (p < end) {                       // predicated tail: 1..7 edges
    int cnt = end - p;
    int s[8]; uint2 v[8]; float w[8];
    #pragma unroll
    for (int j = 0; j < 8; ++j) s[j] = srcs[p + (j < cnt ? j : cnt - 1)];
    #pragma unroll
    for (int j = 0; j < 8; ++j)
      v[j] = *reinterpret_cast<const uint2*>(h1b + (size_t)s[j] * 256 + lane * 4);
    #pragma unroll
    for (int j = 0; j < 8; ++j) {
      float e = a_s[s[j] * 8 + hh] + adh;
      e = e > 0.f ? e : NEG_SLOPE * e;
      w[j] = (j < cnt) ? __expf(e) : 0.f;
    }
    #pragma unroll
    for (int j = 0; j < 8; ++j) {
      float c0 = __uint_as_float(v[j].x << 16);
      float c1 = __uint_as_float(v[j].x & 0xffff0000u);
      float c2 = __uint_as_float(v[j].y << 16);
      float c3 = __uint_as_float(v[j].y & 0xffff0000u);
      sw += w[j];
      acc.x += w[j] * c0; acc.y += w[j] * c1;
      acc.z += w[j] * c2; acc.w += w[j] * c3;
    }
  }
  float inv = 1.f / (sw + 1e-16f);
  float4 b = reinterpret_cast<const float4*>(b1)[lane];
  float4 r;
  r.x = acc.x * inv + b.x;
  r.y = acc.y * inv + b.y;
  r.z = acc.z * inv + b.z;
  r.w = acc.w * inv + b.w;
  r.x = r.x > 0.f ? r.x : (__expf(r.x) - 1.f);   // ELU
  r.y = r.y > 0.f ? r.y : (__expf(r.y) - 1.f);
  r.z = r.z > 0.f ? r.z : (__expf(r.z) - 1.f);
  r.w = r.w > 0.f ? r.w : (__expf(r.w) - 1.f);
  *reinterpret_cast<float4*>(y1 + (size_t)n * 256 + lane * 4) = r;
}

// ---------------- per-node attention logits, layer 2 (f32) ------------------
__global__ void scores2(const float* __restrict__ h2, const float* __restrict__ att_s,
                        const float* __restrict__ att_d, float* __restrict__ a_s,
                        float* __restrict__ a_d, int N) {
  int n = blockIdx.x * blockDim.x + threadIdx.x;
  if (n >= N) return;
  const float4* row = reinterpret_cast<const float4*>(h2 + (size_t)n * 64);
  const float4* as4 = reinterpret_cast<const float4*>(att_s);
  const float4* ad4 = reinterpret_cast<const float4*>(att_d);
  float ss = 0.f, dd = 0.f;
  #pragma unroll
  for (int c = 0; c < 16; ++c) {
    float4 v = row[c], s4 = as4[c], d4 = ad4[c];
    ss += v.x * s4.x + v.y * s4.y + v.z * s4.z + v.w * s4.w;
    dd += v.x * d4.x + v.y * d4.y + v.z * d4.z + v.w * d4.w;
  }
  a_s[n] = ss;
  a_d[n] = dd;
}

// ------ layer-2 aggregation, fused softmax: 1 wave/node, lane = channel -----
__global__ __launch_bounds__(256) void aggregate2(const int* __restrict__ off,
                                                  const int* __restrict__ srcs,
                                                  const float* __restrict__ a_s,
                                                  const float* __restrict__ a_d,
                                                  const float* __restrict__ h2,
                                                  const float* __restrict__ b2,
                                                  float* __restrict__ out, int N) {
  int n = blockIdx.x * 4 + (threadIdx.x >> 6);
  if (n >= N) return;
  int c = threadIdx.x & 63;            // channel 0..63
  float ad = a_d[n];
  int beg = off[n], end = off[n + 1];
  float acc = 0.f;
  float sw = 0.f;
  int p = beg;
  for (; p + 8 <= end; p += 8) {
    int s[8]; float v[8]; float w[8];
    #pragma unroll
    for (int j = 0; j < 8; ++j) s[j] = srcs[p + j];
    #pragma unroll
    for (int j = 0; j < 8; ++j) v[j] = h2[(size_t)s[j] * 64 + c];
    #pragma unroll
    for (int j = 0; j < 8; ++j) {
      float e = a_s[s[j]] + ad;
      e = e > 0.f ? e : NEG_SLOPE * e;
      w[j] = __expf(e);
    }
    #pragma unroll
    for (int j = 0; j < 8; ++j) { sw += w[j]; acc += w[j] * v[j]; }
  }
  if (p < end) {                       // predicated tail
    int cnt = end - p;
    int s[8]; float v[8]; float w[8];
    #pragma unroll
    for (int j = 0; j < 8; ++j) s[j] = srcs[p + (j < cnt ? j : cnt - 1)];
    #pragma unroll
    for (int j = 0; j < 8; ++j) v[j] = h2[(size_t)s[j] * 64 + c];
    #pragma unroll
    for (int j = 0; j < 8; ++j) {
      float e = a_s[s[j]] + ad;
      e = e > 0.f ? e : NEG_SLOPE * e;
      w[j] = (j < cnt) ? __expf(e) : 0.f;
    }
    #pragma unroll
    for (int j = 0; j < 8; ++j) { sw += w[j]; acc += w[j] * v[j]; }
  }
  out[(size_t)n * 64 + c] = acc / (sw + 1e-16f) + b2[c];   // heads=1: mean==id
}

extern "C" void kernel_launch(void* const* d_in, const int* in_sizes, int n_in,
                              void* d_out, int out_size, void* d_ws, size_t ws_size,
                              hipStream_t stream) {
  const float* x   = (const float*)d_in[0];
  const int*   ei  = (const int*)d_in[1];
  const float* W1  = (const float*)d_in[2];
  const float* as1 = (const float*)d_in[3];
  const float* ad1 = (const float*)d_in[4];
  const float* b1  = (const float*)d_in[5];
  const float* W2  = (const float*)d_in[6];
  const float* as2 = (const float*)d_in[7];
  const float* ad2 = (const float*)d_in[8];
  const float* b2  = (const float*)d_in[9];
  float* out = (float*)d_out;

  const int N = in_sizes[0] / 128;   // 50000
  const int E = in_sizes[1] / 2;     // 800000
  const int T = E + N;               // edge slots incl self loops

  // -------- workspace layout (~84 MB peak; h1 is bf16 now) --------
  char* w = (char*)d_ws;
  size_t o = 0;
  auto alloc = [&](size_t bytes) -> void* {
    void* p = w + o;
    o += (bytes + 255) & ~(size_t)255;
    return p;
  };
  unsigned short* h1b = (unsigned short*)alloc((size_t)N * 256 * 2); // dead after aggregate1
  float* y1   = (float*)alloc((size_t)N * 256 * 4);
  float* a_s1 = (float*)alloc((size_t)N * 8 * 4);     // dead after aggregate1
  float* a_d1 = (float*)alloc((size_t)N * 8 * 4);     // dead after aggregate1
  int*   deg  = (int*)alloc((size_t)N * 4);
  int*   off  = (int*)alloc((size_t)(N + 1) * 4);
  int*   cur  = (int*)alloc((size_t)N * 4);
  int*   srcs = (int*)alloc((size_t)T * 4);
  // layer-2 aliases (strictly after last read of the aliased buffer):
  float* h2   = (float*)h1b;          // 12.8 MB f32 inside h1b's 25.6 MB
  float* a_s2 = a_s1;
  float* a_d2 = a_d1;

  // -------- CSR build (shared by both layers) --------
  init_nodes<<<(N + 255) / 256, 256, 0, stream>>>(deg, cur, N);
  count_deg<<<(E + 255) / 256, 256, 0, stream>>>(ei, E, deg);
  scan_deg<<<1, 1024, 0, stream>>>(deg, off, N);
  fill_csr<<<(T + 255) / 256, 256, 0, stream>>>(ei, E, N, off, cur, srcs);

  // -------- layer 1: h1b = bf16(x @ W1)  (50000x128 @ 128x256) --------
  dim3 g1((N + 127) / 128, 2);       // BN=128
  gemm_f32_t<128, 128, 8, unsigned short><<<g1, 256, 0, stream>>>(x, W1, h1b, N, 256, 128);
  scores1<<<(N * 8 + 255) / 256, 256, 0, stream>>>(h1b, as1, ad1, a_s1, a_d1, N);
  aggregate1<<<(N + 3) / 4, 256, 0, stream>>>(off, srcs, a_s1, a_d1, h1b, b1, y1, N);

  // -------- layer 2: h2 = y1 @ W2  (50000x256 @ 256x64), f32 --------
  dim3 g2((N + 127) / 128, 1);       // BN=64
  gemm_f32_t<128, 64, 4, float><<<g2, 256, 0, stream>>>(y1, W2, h2, N, 64, 256);
  scores2<<<(N + 255) / 256, 256, 0, stream>>>(h2, as2, ad2, a_s2, a_d2, N);
  aggregate2<<<(N + 3) / 4, 256, 0, stream>>>(off, srcs, a_s2, a_d2, h2, b2, out, N);
}

// Round 13
// 391.739 us; speedup vs baseline: 1.3226x; 1.1761x over previous
//
#include <hip/hip_runtime.h>
#include <hip/hip_bf16.h>
#include <math.h>

#define NEG_SLOPE 0.2f

// RNE float->bf16 pair pack (finite data; NaN not handled)
__device__ __forceinline__ unsigned int pack_bf16x2(float a, float b) {
  unsigned ua = __float_as_uint(a); ua = ua + 0x7fffu + ((ua >> 16) & 1u);
  unsigned ub = __float_as_uint(b); ub = ub + 0x7fffu + ((ub >> 16) & 1u);
  return (ua >> 16) | (ub & 0xffff0000u);
}

// ------- GEMM f32: BMxBN tile, BK=16, 256 thr, split-fragment micro -------
// CT=float: float4 C-store. CT=ushort: bf16 C-store (uint2 per 4 cols).
template <int BM_, int BN_, int TN_, typename CT>
__global__ __launch_bounds__(256) void gemm_f32_t(const float* __restrict__ A,
                                                  const float* __restrict__ B,
                                                  CT* __restrict__ C,
                                                  int M, int N, int K) {
  constexpr int BK_ = 16;
  constexpr int NJH = TN_ / 4;                 // 1 or 2 column halves
  __shared__ float As[BK_][BM_ + 4];
  __shared__ float Bs[BK_][BN_ + 4];
  const int tid = threadIdx.x;
  const int tx = tid & 15;
  const int ty = tid >> 4;
  const int bm = blockIdx.x * BM_;
  const int bn = blockIdx.y * BN_;
  float acc[2][NJH][4][4] = {};
  for (int k0 = 0; k0 < K; k0 += BK_) {
    #pragma unroll
    for (int i = tid; i < BM_ * 4; i += 256) {   // A: BM_ rows x 16K, transposed
      int r = i >> 2, c4 = i & 3;
      int gr = bm + r;
      float4 v = make_float4(0.f, 0.f, 0.f, 0.f);
      if (gr < M) v = *reinterpret_cast<const float4*>(&A[(size_t)gr * K + k0 + c4 * 4]);
      As[c4 * 4 + 0][r] = v.x;
      As[c4 * 4 + 1][r] = v.y;
      As[c4 * 4 + 2][r] = v.z;
      As[c4 * 4 + 3][r] = v.w;
    }
    #pragma unroll
    for (int i = tid; i < BN_ * 4; i += 256) {   // B: 16K x BN_, row-major
      constexpr int F4 = BN_ / 4;
      int r = i / F4, c4 = i % F4;
      *reinterpret_cast<float4*>(&Bs[r][c4 * 4]) =
          *reinterpret_cast<const float4*>(&B[(size_t)(k0 + r) * N + bn + c4 * 4]);
    }
    __syncthreads();
    #pragma unroll
    for (int kk = 0; kk < BK_; ++kk) {
      float4 a0 = *reinterpret_cast<const float4*>(&As[kk][ty * 4]);
      float4 a1 = *reinterpret_cast<const float4*>(&As[kk][BM_ / 2 + ty * 4]);
      float av[2][4] = {{a0.x, a0.y, a0.z, a0.w}, {a1.x, a1.y, a1.z, a1.w}};
      float bv[NJH][4];
      {
        float4 b0 = *reinterpret_cast<const float4*>(&Bs[kk][tx * 4]);
        bv[0][0] = b0.x; bv[0][1] = b0.y; bv[0][2] = b0.z; bv[0][3] = b0.w;
      }
      if constexpr (NJH == 2) {
        float4 b1 = *reinterpret_cast<const float4*>(&Bs[kk][BN_ / 2 + tx * 4]);
        bv[1][0] = b1.x; bv[1][1] = b1.y; bv[1][2] = b1.z; bv[1][3] = b1.w;
      }
      #pragma unroll
      for (int ih = 0; ih < 2; ++ih)
        #pragma unroll
        for (int jh = 0; jh < NJH; ++jh)
          #pragma unroll
          for (int i = 0; i < 4; ++i)
            #pragma unroll
            for (int j = 0; j < 4; ++j)
              acc[ih][jh][i][j] += av[ih][i] * bv[jh][j];
    }
    __syncthreads();
  }
  #pragma unroll
  for (int ih = 0; ih < 2; ++ih) {
    #pragma unroll
    for (int i = 0; i < 4; ++i) {
      int gr = bm + ih * (BM_ / 2) + ty * 4 + i;
      if (gr < M) {
        #pragma unroll
        for (int jh = 0; jh < NJH; ++jh) {
          size_t cidx = (size_t)gr * N + bn + jh * (BN_ / 2) + tx * 4;
          if constexpr (sizeof(CT) == 4) {
            float4 v = make_float4(acc[ih][jh][i][0], acc[ih][jh][i][1],
                                   acc[ih][jh][i][2], acc[ih][jh][i][3]);
            *reinterpret_cast<float4*>(&C[cidx]) = v;
          } else {
            uint2 q;
            q.x = pack_bf16x2(acc[ih][jh][i][0], acc[ih][jh][i][1]);
            q.y = pack_bf16x2(acc[ih][jh][i][2], acc[ih][jh][i][3]);
            *reinterpret_cast<uint2*>(&C[cidx]) = q;
          }
        }
      }
    }
  }
}

// ---------------- node init: self-loop degree + cursor ----------------------
__global__ void init_nodes(int* deg, int* cursor, int N) {
  int n = blockIdx.x * blockDim.x + threadIdx.x;
  if (n >= N) return;
  deg[n] = 1;        // self loop
  cursor[n] = 0;
}

// ---------------- degree count over real edges ------------------------------
__global__ void count_deg(const int* __restrict__ ei, int E, int* __restrict__ deg) {
  int i = blockIdx.x * blockDim.x + threadIdx.x;
  if (i >= E) return;
  atomicAdd(&deg[ei[E + i]], 1);     // ei[E + i] = dst
}

// ------------- two-level parallel exclusive scan (3 kernels) ----------------
// scan_blk: 256/block Hillis-Steele; off[i] = local exclusive; blksum[b]=total
__global__ __launch_bounds__(256) void scan_blk(const int* __restrict__ deg,
                                                int* __restrict__ off,
                                                int* __restrict__ blksum, int N) {
  __shared__ int sh[256];
  int t = threadIdx.x;
  int i = blockIdx.x * 256 + t;
  int v = (i < N) ? deg[i] : 0;
  sh[t] = v;
  __syncthreads();
  #pragma unroll
  for (int s = 1; s < 256; s <<= 1) {
    int add = (t >= s) ? sh[t - s] : 0;
    __syncthreads();
    sh[t] += add;
    __syncthreads();
  }
  if (i < N) off[i] = sh[t] - v;        // exclusive
  if (t == 255) blksum[blockIdx.x] = sh[255];
}

// scan_top: single block scans <=256 block sums; writes off[N] = grand total
__global__ __launch_bounds__(256) void scan_top(const int* __restrict__ blksum,
                                                int* __restrict__ blkoff,
                                                int nb, int* __restrict__ off, int N) {
  __shared__ int sh[256];
  int t = threadIdx.x;
  int v = (t < nb) ? blksum[t] : 0;
  sh[t] = v;
  __syncthreads();
  #pragma unroll
  for (int s = 1; s < 256; s <<= 1) {
    int add = (t >= s) ? sh[t - s] : 0;
    __syncthreads();
    sh[t] += add;
    __syncthreads();
  }
  if (t < nb) blkoff[t] = sh[t] - v;    // exclusive block offset
  if (t == 255) off[N] = sh[255];       // grand total
}

// scan_add: off[i] += blkoff[block]
__global__ __launch_bounds__(256) void scan_add(int* __restrict__ off,
                                                const int* __restrict__ blkoff, int N) {
  int i = blockIdx.x * 256 + threadIdx.x;
  if (i < N) off[i] += blkoff[blockIdx.x];
}

// ---------------- CSR fill (src list grouped by dst) ------------------------
__global__ void fill_csr(const int* __restrict__ ei, int E, int N,
                         const int* __restrict__ off, int* __restrict__ cursor,
                         int* __restrict__ srcs) {
  int i = blockIdx.x * blockDim.x + threadIdx.x;
  int total = E + N;
  if (i >= total) return;
  int s, d;
  if (i < E) { s = ei[i]; d = ei[E + i]; }
  else       { s = d = i - E; }            // self loops
  int pos = off[d] + atomicAdd(&cursor[d], 1);
  srcs[pos] = s;
}

// ------- per-(node,head) attention logits, layer 1 (bf16 h1 input) ----------
__global__ void scores1(const unsigned short* __restrict__ h1b,
                        const float* __restrict__ att_s,
                        const float* __restrict__ att_d, float* __restrict__ a_s,
                        float* __restrict__ a_d, int N) {
  int idx = blockIdx.x * blockDim.x + threadIdx.x;
  if (idx >= N * 8) return;
  int hh = idx & 7;
  const uint4* row = reinterpret_cast<const uint4*>(h1b + (size_t)(idx >> 3) * 256 + hh * 32);
  const float* as = att_s + hh * 32;
  const float* ad = att_d + hh * 32;
  float ss = 0.f, dd = 0.f;
  #pragma unroll
  for (int c = 0; c < 4; ++c) {
    uint4 q = row[c];
    unsigned qs[4] = {q.x, q.y, q.z, q.w};
    #pragma unroll
    for (int k = 0; k < 4; ++k) {
      float f0 = __uint_as_float(qs[k] << 16);
      float f1 = __uint_as_float(qs[k] & 0xffff0000u);
      int ch = c * 8 + k * 2;
      ss += f0 * as[ch] + f1 * as[ch + 1];
      dd += f0 * ad[ch] + f1 * ad[ch + 1];
    }
  }
  a_s[idx] = ss;
  a_d[idx] = dd;
}

// ------ layer-1 aggregation, fused softmax, bf16 gather: 1 wave/node --------
__global__ __launch_bounds__(256) void aggregate1(const int* __restrict__ off,
                                                  const int* __restrict__ srcs,
                                                  const float* __restrict__ a_s,
                                                  const float* __restrict__ a_d,
                                                  const unsigned short* __restrict__ h1b,
                                                  const float* __restrict__ b1,
                                                  float* __restrict__ y1, int N) {
  int n = blockIdx.x * 4 + (threadIdx.x >> 6);
  if (n >= N) return;
  int lane = threadIdx.x & 63;
  int hh = lane >> 3;
  float adh = a_d[n * 8 + hh];
  int beg = off[n], end = off[n + 1];
  float4 acc = make_float4(0.f, 0.f, 0.f, 0.f);
  float sw = 0.f;
  int p = beg;
  for (; p + 8 <= end; p += 8) {
    int s[8]; uint2 v[8]; float w[8];
    #pragma unroll
    for (int j = 0; j < 8; ++j) s[j] = srcs[p + j];
    #pragma unroll
    for (int j = 0; j < 8; ++j)
      v[j] = *reinterpret_cast<const uint2*>(h1b + (size_t)s[j] * 256 + lane * 4);
    #pragma unroll
    for (int j = 0; j < 8; ++j) {
      float e = a_s[s[j] * 8 + hh] + adh;
      e = e > 0.f ? e : NEG_SLOPE * e;
      w[j] = __expf(e);
    }
    #pragma unroll
    for (int j = 0; j < 8; ++j) {
      float c0 = __uint_as_float(v[j].x << 16);
      float c1 = __uint_as_float(v[j].x & 0xffff0000u);
      float c2 = __uint_as_float(v[j].y << 16);
      float c3 = __uint_as_float(v[j].y & 0xffff0000u);
      sw += w[j];
      acc.x += w[j] * c0; acc.y += w[j] * c1;
      acc.z += w[j] * c2; acc.w += w[j] * c3;
    }
  }
  if (p < end) {                       // predicated tail: 1..7 edges
    int cnt = end - p;
    int s[8]; uint2 v[8]; float w[8];
    #pragma unroll
    for (int j = 0; j < 8; ++j) s[j] = srcs[p + (j < cnt ? j : cnt - 1)];
    #pragma unroll
    for (int j = 0; j < 8; ++j)
      v[j] = *reinterpret_cast<const uint2*>(h1b + (size_t)s[j] * 256 + lane * 4);
    #pragma unroll
    for (int j = 0; j < 8; ++j) {
      float e = a_s[s[j] * 8 + hh] + adh;
      e = e > 0.f ? e : NEG_SLOPE * e;
      w[j] = (j < cnt) ? __expf(e) : 0.f;
    }
    #pragma unroll
    for (int j = 0; j < 8; ++j) {
      float c0 = __uint_as_float(v[j].x << 16);
      float c1 = __uint_as_float(v[j].x & 0xffff0000u);
      float c2 = __uint_as_float(v[j].y << 16);
      float c3 = __uint_as_float(v[j].y & 0xffff0000u);
      sw += w[j];
      acc.x += w[j] * c0; acc.y += w[j] * c1;
      acc.z += w[j] * c2; acc.w += w[j] * c3;
    }
  }
  float inv = 1.f / (sw + 1e-16f);
  float4 b = reinterpret_cast<const float4*>(b1)[lane];
  float4 r;
  r.x = acc.x * inv + b.x;
  r.y = acc.y * inv + b.y;
  r.z = acc.z * inv + b.z;
  r.w = acc.w * inv + b.w;
  r.x = r.x > 0.f ? r.x : (__expf(r.x) - 1.f);   // ELU
  r.y = r.y > 0.f ? r.y : (__expf(r.y) - 1.f);
  r.z = r.z > 0.f ? r.z : (__expf(r.z) - 1.f);
  r.w = r.w > 0.f ? r.w : (__expf(r.w) - 1.f);
  *reinterpret_cast<float4*>(y1 + (size_t)n * 256 + lane * 4) = r;
}

// ---------------- per-node attention logits, layer 2 (f32) ------------------
__global__ void scores2(const float* __restrict__ h2, const float* __restrict__ att_s,
                        const float* __restrict__ att_d, float* __restrict__ a_s,
                        float* __restrict__ a_d, int N) {
  int n = blockIdx.x * blockDim.x + threadIdx.x;
  if (n >= N) return;
  const float4* row = reinterpret_cast<const float4*>(h2 + (size_t)n * 64);
  const float4* as4 = reinterpret_cast<const float4*>(att_s);
  const float4* ad4 = reinterpret_cast<const float4*>(att_d);
  float ss = 0.f, dd = 0.f;
  #pragma unroll
  for (int c = 0; c < 16; ++c) {
    float4 v = row[c], s4 = as4[c], d4 = ad4[c];
    ss += v.x * s4.x + v.y * s4.y + v.z * s4.z + v.w * s4.w;
    dd += v.x * d4.x + v.y * d4.y + v.z * d4.z + v.w * d4.w;
  }
  a_s[n] = ss;
  a_d[n] = dd;
}

// ------ layer-2 aggregation, fused softmax: 1 wave/node, lane = channel -----
__global__ __launch_bounds__(256) void aggregate2(const int* __restrict__ off,
                                                  const int* __restrict__ srcs,
                                                  const float* __restrict__ a_s,
                                                  const float* __restrict__ a_d,
                                                  const float* __restrict__ h2,
                                                  const float* __restrict__ b2,
                                                  float* __restrict__ out, int N) {
  int n = blockIdx.x * 4 + (threadIdx.x >> 6);
  if (n >= N) return;
  int c = threadIdx.x & 63;            // channel 0..63
  float ad = a_d[n];
  int beg = off[n], end = off[n + 1];
  float acc = 0.f;
  float sw = 0.f;
  int p = beg;
  for (; p + 8 <= end; p += 8) {
    int s[8]; float v[8]; float w[8];
    #pragma unroll
    for (int j = 0; j < 8; ++j) s[j] = srcs[p + j];
    #pragma unroll
    for (int j = 0; j < 8; ++j) v[j] = h2[(size_t)s[j] * 64 + c];
    #pragma unroll
    for (int j = 0; j < 8; ++j) {
      float e = a_s[s[j]] + ad;
      e = e > 0.f ? e : NEG_SLOPE * e;
      w[j] = __expf(e);
    }
    #pragma unroll
    for (int j = 0; j < 8; ++j) { sw += w[j]; acc += w[j] * v[j]; }
  }
  if (p < end) {                       // predicated tail
    int cnt = end - p;
    int s[8]; float v[8]; float w[8];
    #pragma unroll
    for (int j = 0; j < 8; ++j) s[j] = srcs[p + (j < cnt ? j : cnt - 1)];
    #pragma unroll
    for (int j = 0; j < 8; ++j) v[j] = h2[(size_t)s[j] * 64 + c];
    #pragma unroll
    for (int j = 0; j < 8; ++j) {
      float e = a_s[s[j]] + ad;
      e = e > 0.f ? e : NEG_SLOPE * e;
      w[j] = (j < cnt) ? __expf(e) : 0.f;
    }
    #pragma unroll
    for (int j = 0; j < 8; ++j) { sw += w[j]; acc += w[j] * v[j]; }
  }
  out[(size_t)n * 64 + c] = acc / (sw + 1e-16f) + b2[c];   // heads=1: mean==id
}

extern "C" void kernel_launch(void* const* d_in, const int* in_sizes, int n_in,
                              void* d_out, int out_size, void* d_ws, size_t ws_size,
                              hipStream_t stream) {
  const float* x   = (const float*)d_in[0];
  const int*   ei  = (const int*)d_in[1];
  const float* W1  = (const float*)d_in[2];
  const float* as1 = (const float*)d_in[3];
  const float* ad1 = (const float*)d_in[4];
  const float* b1  = (const float*)d_in[5];
  const float* W2  = (const float*)d_in[6];
  const float* as2 = (const float*)d_in[7];
  const float* ad2 = (const float*)d_in[8];
  const float* b2  = (const float*)d_in[9];
  float* out = (float*)d_out;

  const int N = in_sizes[0] / 128;   // 50000
  const int E = in_sizes[1] / 2;     // 800000
  const int T = E + N;               // edge slots incl self loops
  const int NB = (N + 255) / 256;    // scan blocks (196 <= 256)

  // -------- workspace layout (~84 MB peak; h1 is bf16) --------
  char* w = (char*)d_ws;
  size_t o = 0;
  auto alloc = [&](size_t bytes) -> void* {
    void* p = w + o;
    o += (bytes + 255) & ~(size_t)255;
    return p;
  };
  unsigned short* h1b = (unsigned short*)alloc((size_t)N * 256 * 2); // dead after aggregate1
  float* y1   = (float*)alloc((size_t)N * 256 * 4);
  float* a_s1 = (float*)alloc((size_t)N * 8 * 4);     // dead after aggregate1
  float* a_d1 = (float*)alloc((size_t)N * 8 * 4);     // dead after aggregate1
  int*   deg  = (int*)alloc((size_t)N * 4);
  int*   off  = (int*)alloc((size_t)(N + 1) * 4);
  int*   cur  = (int*)alloc((size_t)N * 4);
  int*   srcs = (int*)alloc((size_t)T * 4);
  int* blksum = (int*)alloc((size_t)256 * 4);
  int* blkoff = (int*)alloc((size_t)256 * 4);
  // layer-2 aliases (strictly after last read of the aliased buffer):
  float* h2   = (float*)h1b;          // 12.8 MB f32 inside h1b's 25.6 MB
  float* a_s2 = a_s1;
  float* a_d2 = a_d1;

  // -------- CSR build (shared by both layers) --------
  init_nodes<<<(N + 255) / 256, 256, 0, stream>>>(deg, cur, N);
  count_deg<<<(E + 255) / 256, 256, 0, stream>>>(ei, E, deg);
  scan_blk<<<NB, 256, 0, stream>>>(deg, off, blksum, N);
  scan_top<<<1, 256, 0, stream>>>(blksum, blkoff, NB, off, N);
  scan_add<<<NB, 256, 0, stream>>>(off, blkoff, N);
  fill_csr<<<(T + 255) / 256, 256, 0, stream>>>(ei, E, N, off, cur, srcs);

  // -------- layer 1: h1b = bf16(x @ W1)  (50000x128 @ 128x256) --------
  dim3 g1((N + 127) / 128, 2);       // BN=128
  gemm_f32_t<128, 128, 8, unsigned short><<<g1, 256, 0, stream>>>(x, W1, h1b, N, 256, 128);
  scores1<<<(N * 8 + 255) / 256, 256, 0, stream>>>(h1b, as1, ad1, a_s1, a_d1, N);
  aggregate1<<<(N + 3) / 4, 256, 0, stream>>>(off, srcs, a_s1, a_d1, h1b, b1, y1, N);

  // -------- layer 2: h2 = y1 @ W2  (50000x256 @ 256x64), f32 --------
  dim3 g2((N + 127) / 128, 1);       // BN=64
  gemm_f32_t<128, 64, 4, float><<<g2, 256, 0, stream>>>(y1, W2, h2, N, 64, 256);
  scores2<<<(N + 255) / 256, 256, 0, stream>>>(h2, as2, ad2, a_s2, a_d2, N);
  aggregate2<<<(N + 3) / 4, 256, 0, stream>>>(off, srcs, a_s2, a_d2, h2, b2, out, N);
}